// Round 3
// baseline (1066.832 us; speedup 1.0000x reference)
//
#include <hip/hip_runtime.h>
#include <stdint.h>

// Baum-Welch forward-backward posteriors (log_gamma), MI355X gfx950.
//
// R6 -> R7 (theory: R6's apair[4][16] = 128 floats/lane could not fit the
// 128-VGPR budget -> compiler shadowed it in AGPRs -> ~128 v_accvgpr_read
// per lane per step dominated VALU issue (VALUBusy 43%, 2260 cy/step).
//  - 1024 threads (16 waves, 4/SIMD): per-lane A = 2 outputs x 32 inputs
//    = 64 floats -> truly VGPR-resident. Per-lane FMA work halves.
//  - Input-chunk index in LOW lane bits (ic = c&7): cross-chunk reduce uses
//    masks ^1/^2/^4 -> full-rate DPP butterflies (quad_perm 0xB1, 0x4E,
//    half_mirror∘quad_reverse), zero LDS-class ops in the reduce.
//  - Same scaled exp-domain recurrence, one lgkmcnt-only barrier per step,
//    16-slot rbuf with 8-step flush cadence (f2/thread at 1024 threads),
//    uniform rescale by rcp(prev_staged[0]), gamma_norm streaming pass.

#define NB 256
#define TT 512
#define KK 256
#define VV 4096
#define LOG2E 1.44269504088896f
#define LN2 0.693147180559945f

typedef float f2 __attribute__((ext_vector_type(2)));
typedef float f4 __attribute__((ext_vector_type(4)));

__device__ __forceinline__ void bar_lds() {
  // Workgroup barrier draining LDS only (global loads/stores stay in flight).
  asm volatile("s_waitcnt lgkmcnt(0)" ::: "memory");
  __builtin_amdgcn_s_barrier();
}

// Butterfly add over lane bits 0..2 (8 replicas), all full-rate DPP:
//   ^1 = quad_perm [1,0,3,2] (0xB1), ^2 = quad_perm [2,3,0,1] (0x4E),
//   ^4 = row_half_mirror (^7, 0x141) then quad reverse (^3, 0x1B).
__device__ __forceinline__ float red8(float x) {
  int t;
  t = __builtin_amdgcn_update_dpp(0, __float_as_int(x), 0xB1, 0xF, 0xF, true);
  x += __int_as_float(t);
  t = __builtin_amdgcn_update_dpp(0, __float_as_int(x), 0x4E, 0xF, 0xF, true);
  x += __int_as_float(t);
  t = __builtin_amdgcn_update_dpp(0, __float_as_int(x), 0x141, 0xF, 0xF, true);
  t = __builtin_amdgcn_update_dpp(0, t, 0x1B, 0xF, 0xF, true);
  x += __int_as_float(t);
  return x;
}

// MODE 0: forward (stores scaled alpha rows to gout).
// MODE 1: backward (overwrites gout rows with scaled alpha*beta, high t first).
template <int MODE>
__global__ __launch_bounds__(1024, 4) void hmm_recur(
    const float* __restrict__ lpi, const float* __restrict__ lA,
    const float* __restrict__ lB, const int* __restrict__ obs,
    float* __restrict__ gout) {
  const int n = blockIdx.x;
  const int tid = threadIdx.x;  // 0..1023
  const int g = tid >> 6;       // wave id: owns output states [16g, 16g+16)
  const int c = tid & 63;
  const int ic = c & 7;         // input chunk: [32*ic, 32*ic+32)
  const int oc = c >> 3;        // 0..7
  const bool wr = (ic == 0);    // 8 writer lanes per wave, 2 outputs each
  const int jo0 = 16 * g + oc;  // this lane's two output states
  const int jo1 = jo0 + 8;

  __shared__ int obs_s[TT];                      // 2 KB
  __shared__ __align__(16) float avec[2][288];   // ping-pong staged vector,
                                                 // 8 chunks of 36 (32 + 4 pad)
  __shared__ __align__(16) float rbuf[16][KK];   // 16 KB batched output rows

  for (int i = tid; i < TT; i += 1024) obs_s[i] = obs[n * TT + i];

  // Register-resident exp(A): 2 outputs x 32 inputs per lane, f2-packed.
  // fwd: columns A[i][jo] (alpha recurrence); bwd: rows A[jo][i] (beta).
  f2 ap0[16], ap1[16];
#pragma unroll
  for (int k = 0; k < 16; ++k) {
    const int i0 = 32 * ic + 2 * k;
    float e00, e01, e10, e11;
    if (MODE == 0) {
      e00 = lA[(size_t)i0 * KK + jo0];
      e01 = lA[(size_t)(i0 + 1) * KK + jo0];
      e10 = lA[(size_t)i0 * KK + jo1];
      e11 = lA[(size_t)(i0 + 1) * KK + jo1];
    } else {
      e00 = lA[(size_t)jo0 * KK + i0];
      e01 = lA[(size_t)jo0 * KK + i0 + 1];
      e10 = lA[(size_t)jo1 * KK + i0];
      e11 = lA[(size_t)jo1 * KK + i0 + 1];
    }
    f2 p0; p0[0] = exp2f(e00 * LOG2E); p0[1] = exp2f(e01 * LOG2E);
    f2 p1; p1[0] = exp2f(e10 * LOG2E); p1[1] = exp2f(e11 * LOG2E);
    ap0[k] = p0;
    ap1[k] = p1;
  }

  // Precomputed per-lane addresses.
  const int wA0 = 36 * (jo0 >> 5) + (jo0 & 31);  // avec slot for jo0
  const int wA1 = 36 * (jo1 >> 5) + (jo1 & 31);
  const float* lB0 = lB + (size_t)jo0 * VV;
  const float* lB1 = lB + (size_t)jo1 * VV;
  __syncthreads();  // obs_s ready

  // Dot for this lane's 2 outputs over the staged vector chunk, then DPP
  // butterfly across the 8 chunk replicas (lane bits 0..2).
  auto dot2 = [&](const float* src, float& s0, float& s1) {
    const f4* s4 = (const f4*)(src + 36 * ic);
    f2 aL0 = (f2)0.f, aH0 = (f2)0.f, aL1 = (f2)0.f, aH1 = (f2)0.f;
#pragma unroll
    for (int m = 0; m < 8; ++m) {
      const f4 x = s4[m];
      f2 xl; xl[0] = x[0]; xl[1] = x[1];
      f2 xh; xh[0] = x[2]; xh[1] = x[3];
      aL0 += xl * ap0[2 * m]; aH0 += xh * ap0[2 * m + 1];
      aL1 += xl * ap1[2 * m]; aH1 += xh * ap1[2 * m + 1];
    }
    s0 = red8((aL0[0] + aL0[1]) + (aH0[0] + aH0[1]));
    s1 = red8((aL1[0] + aL1[1]) + (aH1[0] + aH1[1]));
  };

  if (MODE == 0) {
    // ---- forward ----
    float bl0 = 0.f, bl1 = 0.f;  // prefetched raw lB for the next step
    if (wr) {
      const int o0 = obs_s[0];
      float u0 = exp2f((lpi[jo0] + lB0[o0]) * LOG2E);
      float u1 = exp2f((lpi[jo1] + lB1[o0]) * LOG2E);
      avec[0][wA0] = u0;
      avec[0][wA1] = u1;
      rbuf[0][jo0] = u0;
      rbuf[0][jo1] = u1;
      bl0 = lB0[obs_s[1]];
      bl1 = lB1[obs_s[1]];
    }
    __syncthreads();

#pragma unroll 1
    for (int t = 1; t < TT; ++t) {
      float bln0 = 0.f, bln1 = 0.f;
      if (wr && t + 1 < TT) {
        const int on = obs_s[t + 1];
        bln0 = lB0[on];
        bln1 = lB1[on];
      }
      const float* src = avec[(t + 1) & 1];
      const float ref = fmaxf(src[0], 1e-35f);  // broadcast uniform scale
      float s0, s1;
      dot2(src, s0, s1);
      if (wr) {
        const float r = __builtin_amdgcn_rcpf(ref);
        const float u0 = s0 * r * exp2f(bl0 * LOG2E);
        const float u1 = s1 * r * exp2f(bl1 * LOG2E);
        avec[t & 1][wA0] = u0;
        avec[t & 1][wA1] = u1;
        rbuf[t & 15][jo0] = u0;
        rbuf[t & 15][jo1] = u1;
      }
      bl0 = bln0;
      bl1 = bln1;
      bar_lds();
      if ((t & 7) == 7) {
        // flush alpha rows t-7..t: 2048 floats, f2 per thread.
        const int row = t - 7 + (tid >> 7);
        const int col = (tid & 127) * 2;
        const f2 v = *(const f2*)&rbuf[row & 15][col];
        *(f2*)&gout[((size_t)n * TT + row) * KK + col] = v;
      }
    }
  } else {
    // ---- backward: overwrite gout rows with scaled alpha*beta ----
    float bl0 = 0.f, bl1 = 0.f, avp0 = 0.f, avp1 = 0.f;
    if (wr) {
      const int oT = obs_s[TT - 1];
      const size_t rb = (size_t)n * TT * KK;
      avec[1][wA0] = exp2f(lB0[oT] * LOG2E);  // staged w_{T-1} (beta=1)
      avec[1][wA1] = exp2f(lB1[oT] * LOG2E);
      rbuf[15][jo0] = gout[rb + (size_t)(TT - 1) * KK + jo0];  // gg row T-1
      rbuf[15][jo1] = gout[rb + (size_t)(TT - 1) * KK + jo1];
      avp0 = gout[rb + (size_t)(TT - 2) * KK + jo0];
      avp1 = gout[rb + (size_t)(TT - 2) * KK + jo1];
      bl0 = lB0[obs_s[TT - 2]];
      bl1 = lB1[obs_s[TT - 2]];
    }
    __syncthreads();

#pragma unroll 1
    for (int t = TT - 2; t >= 0; --t) {
      float avn0 = 0.f, avn1 = 0.f, bln0 = 0.f, bln1 = 0.f;
      if (wr && t > 0) {
        const float* arow = gout + ((size_t)n * TT + (t - 1)) * KK;
        avn0 = arow[jo0];
        avn1 = arow[jo1];
        const int on = obs_s[t - 1];
        bln0 = lB0[on];
        bln1 = lB1[on];
      }
      const float* src = avec[(t + 1) & 1];  // staged w_{t+1}
      const float ref = fmaxf(src[0], 1e-35f);
      float s0, s1;
      dot2(src, s0, s1);
      if (wr) {
        const float r = __builtin_amdgcn_rcpf(ref);
        const float b0 = s0 * r;  // scaled beta_t
        const float b1 = s1 * r;
        avec[t & 1][wA0] = b0 * exp2f(bl0 * LOG2E);  // staged w_t
        avec[t & 1][wA1] = b1 * exp2f(bl1 * LOG2E);
        rbuf[t & 15][jo0] = avp0 * b0;  // gamma numerator row t
        rbuf[t & 15][jo1] = avp1 * b1;
      }
      avp0 = avn0;
      avp1 = avn1;
      bl0 = bln0;
      bl1 = bln1;
      bar_lds();
      if ((t & 7) == 0) {
        // flush gg rows t..t+7 (rows >= t only; prefetches read rows < t)
        const int row = t + (tid >> 7);
        const int col = (tid & 127) * 2;
        const f2 v = *(const f2*)&rbuf[row & 15][col];
        *(f2*)&gout[((size_t)n * TT + row) * KK + col] = v;
      }
    }
  }
}

// Pass 3: log-normalize each (n,t) row of 256 positive scaled alpha*beta
// values in place: out = (log2(v) - log2(sum v)) * ln2. Pure streaming.
__global__ __launch_bounds__(256) void gamma_norm(float* __restrict__ gout) {
  const int wave = blockIdx.x * 4 + (threadIdx.x >> 6);
  const int c = threadIdx.x & 63;
  const int stride = gridDim.x * 4;
#pragma unroll 1
  for (int row = wave; row < NB * TT; row += stride) {
    float* p = gout + (size_t)row * KK + c * 4;
    const f4 v = *(const f4*)p;
    float s = (v[0] + v[1]) + (v[2] + v[3]);
#pragma unroll
    for (int d = 1; d < 64; d <<= 1) s += __shfl_xor(s, d);
    const float lg = __log2f(s);
    f4 o;
    o[0] = (__log2f(v[0]) - lg) * LN2;
    o[1] = (__log2f(v[1]) - lg) * LN2;
    o[2] = (__log2f(v[2]) - lg) * LN2;
    o[3] = (__log2f(v[3]) - lg) * LN2;
    *(f4*)p = o;
  }
}

extern "C" void kernel_launch(void* const* d_in, const int* in_sizes, int n_in,
                              void* d_out, int out_size, void* d_ws, size_t ws_size,
                              hipStream_t stream) {
  const float* lpi = (const float*)d_in[0];
  const float* lA = (const float*)d_in[1];
  const float* lB = (const float*)d_in[2];
  const int* obs = (const int*)d_in[3];
  float* gout = (float*)d_out;
  (void)d_ws; (void)ws_size;  // deliberately unused

  hmm_recur<0><<<NB, 1024, 0, stream>>>(lpi, lA, lB, obs, gout);
  hmm_recur<1><<<NB, 1024, 0, stream>>>(lpi, lA, lB, obs, gout);
  gamma_norm<<<2048, 256, 0, stream>>>(gout);
}